// Round 3
// baseline (22099.013 us; speedup 1.0000x reference)
//
#include <hip/hip_runtime.h>
#include <math.h>

// ---------------------------------------------------------------------------
// UAVEnhancedModel: LSTM-with-decay + per-step LayerNorm recurrence (S=4096,
// I=512, H=1024) + uav feature path + sigmoid head.
//
//   1) gemm_xp: x_proj = x @ W_ih^T + (b_ih + b_hh)          [4096 x 4096]
//   2) gemm_uf: uf = relu(uav*W1^T + b1) @ W2^T + b2          [4096 x 1024]
//   3) scan:   64 blocks x 1024 threads; block b owns units 16b..16b+15,
//      wave w owns unit 16b+w (its 4 gate rows; 16 lanes per gate row;
//      64 W_hh*ln_g weights per thread in VGPRs).
//      Sync is DATA-FLOW: hn[] sentinel-filled; producers (lane 0 of each
//      wave) store h via agent-scope atomics; ONLY WAVE 0 of each block
//      polls the full 1024-row (slot-major, lane-coalesced) -> LDS.
//      Wave 0 also computes LN stats during the poll (it holds the row).
//      ONE __syncthreads per step (double-buffered LDS row).
//      LayerNorm folded into the matvec: gates = xp + rstd*(dot(W*g,h)
//      - mu*Ar) + Br with Ar=sum(W*g), Br=sum(W*ln_b) per row.
//   4) final:  out[t] = sigmoid(ufcW @ h_ln_t + ufcb); also h_last, c_last.
// ---------------------------------------------------------------------------

constexpr int kS  = 4096;
constexpr int kI  = 512;
constexpr int kH  = 1024;
constexpr int kG4 = 4096;   // 4*kH
constexpr int kNB = 64;     // scan blocks
constexpr float kLnEps = 1e-5f;
constexpr float kWdEps = 1e-7f;
constexpr float kSent  = 1e30f;   // h is clipped to [-10,10] -> unreachable

__device__ __forceinline__ float sigm(float x) { return 1.f / (1.f + expf(-x)); }

__device__ __forceinline__ float ag_load(const float* p) {
  return __hip_atomic_load(p, __ATOMIC_RELAXED, __HIP_MEMORY_SCOPE_AGENT);
}

// ---------------- init: fill hn with sentinel ----------------
__global__ __launch_bounds__(256) void init_hn_kernel(float4* __restrict__ p) {
  const int i = blockIdx.x * 256 + threadIdx.x;   // 4096*256 float4 = S*H floats
  p[i] = make_float4(kSent, kSent, kSent, kSent);
}

// ---------------- GEMM1: xp[s,r] = sum_k x[s,k]*W_ih[r,k] + bias[r] -------
__global__ __launch_bounds__(256) void gemm_xp_kernel(
    const float* __restrict__ A,     // x [4096,512] row-major
    const float* __restrict__ B,     // W_ih [4096,512] row-major
    const float* __restrict__ b_ih, const float* __restrict__ b_hh,
    float* __restrict__ C)           // xp [4096,4096]
{
  __shared__ float As[32][68];
  __shared__ float Bs[32][68];
  const int bm = blockIdx.x * 64, bn = blockIdx.y * 64;
  const int tid = threadIdx.x;
  const int tx = tid & 15, ty = tid >> 4;
  float acc[4][4] = {};
  for (int k0 = 0; k0 < kI; k0 += 32) {
#pragma unroll
    for (int h = 0; h < 2; ++h) {
      const int f = tid + h * 256;
      const int row = f >> 3, c4 = (f & 7) * 4;
      const float4 a  = *(const float4*)(A + (size_t)(bm + row) * kI + k0 + c4);
      const float4 bb = *(const float4*)(B + (size_t)(bn + row) * kI + k0 + c4);
      As[c4 + 0][row] = a.x;  As[c4 + 1][row] = a.y;
      As[c4 + 2][row] = a.z;  As[c4 + 3][row] = a.w;
      Bs[c4 + 0][row] = bb.x; Bs[c4 + 1][row] = bb.y;
      Bs[c4 + 2][row] = bb.z; Bs[c4 + 3][row] = bb.w;
    }
    __syncthreads();
#pragma unroll
    for (int k = 0; k < 32; ++k) {
      const float4 a  = *(const float4*)&As[k][ty * 4];
      const float4 bb = *(const float4*)&Bs[k][tx * 4];
      const float av[4] = {a.x, a.y, a.z, a.w};
      const float bv[4] = {bb.x, bb.y, bb.z, bb.w};
#pragma unroll
      for (int i = 0; i < 4; ++i)
#pragma unroll
        for (int j = 0; j < 4; ++j) acc[i][j] += av[i] * bv[j];
    }
    __syncthreads();
  }
  const float4 bi = *(const float4*)(b_ih + bn + tx * 4);
  const float4 bh = *(const float4*)(b_hh + bn + tx * 4);
  const float4 bias = make_float4(bi.x + bh.x, bi.y + bh.y, bi.z + bh.z, bi.w + bh.w);
#pragma unroll
  for (int i = 0; i < 4; ++i) {
    float4 o = make_float4(acc[i][0] + bias.x, acc[i][1] + bias.y,
                           acc[i][2] + bias.z, acc[i][3] + bias.w);
    *(float4*)(C + (size_t)(bm + ty * 4 + i) * kG4 + bn + tx * 4) = o;
  }
}

// ---------------- GEMM2: uf = relu(uav*W1^T + b1) @ W2^T + b2 ----------------
__global__ __launch_bounds__(256) void gemm_uf_kernel(
    const float* __restrict__ uav,
    const float* __restrict__ W1, const float* __restrict__ b1,
    const float* __restrict__ W2,
    const float* __restrict__ b2,
    float* __restrict__ C)           // uf [4096,1024]
{
  __shared__ float As[32][68];
  __shared__ float Bs[32][68];
  __shared__ float uav_s[64];
  const int bm = blockIdx.x * 64, bn = blockIdx.y * 64;
  const int tid = threadIdx.x;
  const int tx = tid & 15, ty = tid >> 4;
  if (tid < 64) uav_s[tid] = uav[bm + tid];
  __syncthreads();
  float acc[4][4] = {};
  for (int k0 = 0; k0 < kH; k0 += 32) {
#pragma unroll
    for (int h = 0; h < 2; ++h) {
      const int f = tid + h * 256;
      const int row = f >> 3, c4 = (f & 7) * 4;
      const float4 w1v = *(const float4*)(W1 + k0 + c4);
      const float4 b1v = *(const float4*)(b1 + k0 + c4);
      const float ua = uav_s[row];
      As[c4 + 0][row] = fmaxf(ua * w1v.x + b1v.x, 0.f);
      As[c4 + 1][row] = fmaxf(ua * w1v.y + b1v.y, 0.f);
      As[c4 + 2][row] = fmaxf(ua * w1v.z + b1v.z, 0.f);
      As[c4 + 3][row] = fmaxf(ua * w1v.w + b1v.w, 0.f);
      const float4 bb = *(const float4*)(W2 + (size_t)(bn + row) * kH + k0 + c4);
      Bs[c4 + 0][row] = bb.x; Bs[c4 + 1][row] = bb.y;
      Bs[c4 + 2][row] = bb.z; Bs[c4 + 3][row] = bb.w;
    }
    __syncthreads();
#pragma unroll
    for (int k = 0; k < 32; ++k) {
      const float4 a  = *(const float4*)&As[k][ty * 4];
      const float4 bb = *(const float4*)&Bs[k][tx * 4];
      const float av[4] = {a.x, a.y, a.z, a.w};
      const float bv[4] = {bb.x, bb.y, bb.z, bb.w};
#pragma unroll
      for (int i = 0; i < 4; ++i)
#pragma unroll
        for (int j = 0; j < 4; ++j) acc[i][j] += av[i] * bv[j];
    }
    __syncthreads();
  }
  const float4 b2v = *(const float4*)(b2 + bn + tx * 4);
#pragma unroll
  for (int i = 0; i < 4; ++i) {
    float4 o = make_float4(acc[i][0] + b2v.x, acc[i][1] + b2v.y,
                           acc[i][2] + b2v.z, acc[i][3] + b2v.w);
    *(float4*)(C + (size_t)(bm + ty * 4 + i) * kH + bn + tx * 4) = o;
  }
}

// ---------------- persistent scan kernel ----------------
// 64 blocks x 1024 threads (16 waves). Block b: units j0=16b..16b+15.
// Wave w = unit j0+w. Lane group g (lanes 16g..16g+15) = gate row
// row = g*1024 + j0 + w. Thread (g, idx): w[4*mm+e] =
// (W_hh[row][4*idx+64*mm+e] * ln_g[...]). Wave 0 polls + LN stats.
__global__ __launch_bounds__(1024) void scan_kernel(
    const float* __restrict__ xp,     // [S,4H] ws
    const float* __restrict__ uf,     // [S,H]  ws
    float* hn,                        // [S,H]  ws (sentinel-initialized)
    const float* __restrict__ W_hh,   // [4H,H]
    const float* __restrict__ deltas, // [S]
    const float* __restrict__ Wd,     // [H]
    const float* __restrict__ ln_g,   // [H]
    const float* __restrict__ ln_b,   // [H]
    float* __restrict__ out)          // d_out (c_last slice)
{
  const int b = blockIdx.x;
  const int tid = threadIdx.x;
  const int wid = tid >> 6, lane = tid & 63;
  const int g = lane >> 4, idx = lane & 15;
  const int j0 = b * 16;
  const int unit = j0 + wid;
  const int row = g * kH + unit;

  __shared__ float hbuf[2][kH];
  __shared__ float xps[2][64];
  __shared__ float ufs[2][16];
  __shared__ float aux[2][4];       // mu, rstd, delta

  // --- load weights (scaled by ln_g) + fold constants Ar, Br ---
  float w[64];
  float Ar = 0.f, Br = 0.f;
#pragma unroll
  for (int mm = 0; mm < 16; ++mm) {
    const int base = 4 * idx + 64 * mm;
    const float4 wv  = *(const float4*)(W_hh + (size_t)row * kH + base);
    const float4 gg4 = *(const float4*)(ln_g + base);
    const float4 bb4 = *(const float4*)(ln_b + base);
    Br += wv.x * bb4.x + wv.y * bb4.y + wv.z * bb4.z + wv.w * bb4.w;
    w[4 * mm + 0] = wv.x * gg4.x; w[4 * mm + 1] = wv.y * gg4.y;
    w[4 * mm + 2] = wv.z * gg4.z; w[4 * mm + 3] = wv.w * gg4.w;
    Ar += w[4 * mm + 0] + w[4 * mm + 1] + w[4 * mm + 2] + w[4 * mm + 3];
  }
#pragma unroll
  for (int d = 1; d < 16; d <<= 1) {
    Ar += __shfl_xor(Ar, d, 64);
    Br += __shfl_xor(Br, d, 64);
  }

  float c_state = 0.f, wdc = 0.f;
  if (lane == 0) wdc = fminf(fmaxf(Wd[unit], kWdEps), 10.f);

  for (int t = 0; t < kS; ++t) {
    const int buf = t & 1;
    if (wid == 0) {
      // prefetch streamed operands (fully-used 64B lines)
      const float xpv = xp[(size_t)t * kG4 + (lane >> 4) * kH + j0 + (lane & 15)];
      float ufv = 0.f;
      if (lane < 16) ufv = uf[(size_t)t * kH + j0 + lane];
      const float dl = deltas[t];
      if (t > 0) {
        // ---- slot-major coherent poll of full row hn[t-1] ----
        const float* hp = hn + (size_t)(t - 1) * kH + 4 * lane;
        float4 q0, q1, q2, q3;
        bool d0 = false, d1 = false, d2 = false, d3 = false;
        do {
          if (!d0) {
            q0.x = ag_load(hp + 0);   q0.y = ag_load(hp + 1);
            q0.z = ag_load(hp + 2);   q0.w = ag_load(hp + 3);
            d0 = (q0.x != kSent) && (q0.y != kSent) && (q0.z != kSent) && (q0.w != kSent);
          }
          if (!d1) {
            q1.x = ag_load(hp + 256); q1.y = ag_load(hp + 257);
            q1.z = ag_load(hp + 258); q1.w = ag_load(hp + 259);
            d1 = (q1.x != kSent) && (q1.y != kSent) && (q1.z != kSent) && (q1.w != kSent);
          }
          if (!d2) {
            q2.x = ag_load(hp + 512); q2.y = ag_load(hp + 513);
            q2.z = ag_load(hp + 514); q2.w = ag_load(hp + 515);
            d2 = (q2.x != kSent) && (q2.y != kSent) && (q2.z != kSent) && (q2.w != kSent);
          }
          if (!d3) {
            q3.x = ag_load(hp + 768); q3.y = ag_load(hp + 769);
            q3.z = ag_load(hp + 770); q3.w = ag_load(hp + 771);
            d3 = (q3.x != kSent) && (q3.y != kSent) && (q3.z != kSent) && (q3.w != kSent);
          }
        } while (!(d0 && d1 && d2 && d3));
        // LN stats from registers (wave 0 holds the whole row)
        float s1 = q0.x + q0.y + q0.z + q0.w + q1.x + q1.y + q1.z + q1.w +
                   q2.x + q2.y + q2.z + q2.w + q3.x + q3.y + q3.z + q3.w;
        float s2 = q0.x*q0.x + q0.y*q0.y + q0.z*q0.z + q0.w*q0.w +
                   q1.x*q1.x + q1.y*q1.y + q1.z*q1.z + q1.w*q1.w +
                   q2.x*q2.x + q2.y*q2.y + q2.z*q2.z + q2.w*q2.w +
                   q3.x*q3.x + q3.y*q3.y + q3.z*q3.z + q3.w*q3.w;
#pragma unroll
        for (int d = 1; d < 64; d <<= 1) {
          s1 += __shfl_xor(s1, d, 64);
          s2 += __shfl_xor(s2, d, 64);
        }
        const float mu = s1 * (1.f / kH);
        const float var = s2 * (1.f / kH) - mu * mu;
        const float rstd = 1.f / sqrtf(var + kLnEps);
        *(float4*)&hbuf[buf][      4 * lane] = q0;
        *(float4*)&hbuf[buf][256 + 4 * lane] = q1;
        *(float4*)&hbuf[buf][512 + 4 * lane] = q2;
        *(float4*)&hbuf[buf][768 + 4 * lane] = q3;
        if (lane == 0) { aux[buf][0] = mu; aux[buf][1] = rstd; aux[buf][2] = dl; }
      } else {
        if (lane == 0) aux[buf][2] = dl;
      }
      xps[buf][lane] = xpv;
      if (lane < 16) ufs[buf][lane] = ufv;
    }
    __syncthreads();   // row t-1 + operands ready (single barrier per step)

    float gatev = xps[buf][g * 16 + wid];
    if (t > 0) {
      const float mu = aux[buf][0], rstd = aux[buf][1];
      float acc = 0.f;
#pragma unroll
      for (int mm = 0; mm < 16; ++mm) {
        const float4 h4 = *(const float4*)&hbuf[buf][4 * idx + 64 * mm];
        acc += w[4 * mm + 0] * h4.x + w[4 * mm + 1] * h4.y +
               w[4 * mm + 2] * h4.z + w[4 * mm + 3] * h4.w;
      }
#pragma unroll
      for (int d = 1; d < 16; d <<= 1) acc += __shfl_xor(acc, d, 64);
      gatev += rstd * (acc - mu * Ar) + Br;
    }
    // gates of this wave's unit live at lanes 0,16,32,48 (uniform per group)
    const float gi  = __shfl(gatev, 0, 64);
    const float gf  = __shfl(gatev, 16, 64);
    const float gg_ = __shfl(gatev, 32, 64);
    const float go  = __shfl(gatev, 48, 64);
    if (lane == 0) {
      const float dl = aux[buf][2];
      const float dec = expf(-dl * wdc);
      const float cn_u = sigm(gf) * (c_state * dec) + sigm(gi) * tanhf(gg_);
      float hv = sigm(go) * tanhf(cn_u) + 1.5f * ufs[buf][wid];   // tanh of UNclipped c
      hv = fminf(fmaxf(hv, -10.f), 10.f);
      // publish ASAP: consumers poll this word directly
      __hip_atomic_store(hn + (size_t)t * kH + unit, hv,
                         __ATOMIC_RELAXED, __HIP_MEMORY_SCOPE_AGENT);
      c_state = fminf(fmaxf(cn_u, -10.f), 10.f);
    }
  }
  if (lane == 0) out[kS + kH + unit] = c_state;   // c_last
}

// ---------------- final pass: out[t], h_last ----------------
__global__ __launch_bounds__(256) void final_kernel(
    const float* __restrict__ hn, const float* __restrict__ ufcW,
    const float* __restrict__ ufcb, const float* __restrict__ ln_g,
    const float* __restrict__ ln_b, float* __restrict__ out)
{
  const int t = blockIdx.x, tid = threadIdx.x;
  __shared__ float red[4][5];
  __shared__ float muv[2];
  const float4 hv = *(const float4*)(hn + (size_t)t * kH + 4 * tid);
  const float4 uw = *(const float4*)(ufcW + 4 * tid);
  const float4 g4 = *(const float4*)(ln_g + 4 * tid);
  const float4 b4 = *(const float4*)(ln_b + 4 * tid);
  float s1 = hv.x + hv.y + hv.z + hv.w;
  float s2 = hv.x * hv.x + hv.y * hv.y + hv.z * hv.z + hv.w * hv.w;
  float p  = uw.x * g4.x * hv.x + uw.y * g4.y * hv.y + uw.z * g4.z * hv.z + uw.w * g4.w * hv.w;
  float uu = uw.x * g4.x + uw.y * g4.y + uw.z * g4.z + uw.w * g4.w;
  float cc = uw.x * b4.x + uw.y * b4.y + uw.z * b4.z + uw.w * b4.w;
#pragma unroll
  for (int d = 1; d < 64; d <<= 1) {
    s1 += __shfl_xor(s1, d, 64); s2 += __shfl_xor(s2, d, 64);
    p  += __shfl_xor(p, d, 64);  uu += __shfl_xor(uu, d, 64);
    cc += __shfl_xor(cc, d, 64);
  }
  if ((tid & 63) == 0) {
    const int wv = tid >> 6;
    red[wv][0] = s1; red[wv][1] = s2; red[wv][2] = p; red[wv][3] = uu; red[wv][4] = cc;
  }
  __syncthreads();
  if (tid == 0) {
    float S1 = 0, S2 = 0, P = 0, U = 0, C = 0;
    for (int wv = 0; wv < 4; ++wv) {
      S1 += red[wv][0]; S2 += red[wv][1]; P += red[wv][2];
      U += red[wv][3];  C += red[wv][4];
    }
    const float mu = S1 * (1.f / kH);
    const float var = S2 * (1.f / kH) - mu * mu;
    const float rstd = 1.f / sqrtf(var + kLnEps);
    const float val = rstd * (P - mu * U) + C + ufcb[0];
    out[t] = 1.f / (1.f + expf(-val));
    muv[0] = mu; muv[1] = rstd;
  }
  if (t == kS - 1) {   // h_last = h_ln of final step
    __syncthreads();
    const float mu = muv[0], rstd = muv[1];
    out[kS + 4 * tid + 0] = (hv.x - mu) * rstd * g4.x + b4.x;
    out[kS + 4 * tid + 1] = (hv.y - mu) * rstd * g4.y + b4.y;
    out[kS + 4 * tid + 2] = (hv.z - mu) * rstd * g4.z + b4.z;
    out[kS + 4 * tid + 3] = (hv.w - mu) * rstd * g4.w + b4.w;
  }
}

// ---------------- launch ----------------
extern "C" void kernel_launch(void* const* d_in, const int* in_sizes, int n_in,
                              void* d_out, int out_size, void* d_ws, size_t ws_size,
                              hipStream_t stream) {
  (void)in_sizes; (void)n_in; (void)out_size; (void)ws_size;
  const float* x      = (const float*)d_in[0];
  const float* deltas = (const float*)d_in[1];
  const float* uavf   = (const float*)d_in[2];
  const float* W_ih   = (const float*)d_in[3];
  const float* W_hh   = (const float*)d_in[4];
  const float* b_ih   = (const float*)d_in[5];
  const float* b_hh   = (const float*)d_in[6];
  const float* Wd     = (const float*)d_in[7];
  const float* uavW1  = (const float*)d_in[8];
  const float* uavb1  = (const float*)d_in[9];
  const float* uavW2  = (const float*)d_in[10];
  const float* uavb2  = (const float*)d_in[11];
  const float* ufcW   = (const float*)d_in[12];
  const float* ufcb   = (const float*)d_in[13];
  const float* ln_g   = (const float*)d_in[14];
  const float* ln_b   = (const float*)d_in[15];
  float* out = (float*)d_out;

  // ws layout (floats): xp 16777216 | uf 4194304 | hn 4194304
  float* ws = (float*)d_ws;
  float* xp = ws;
  float* uf = ws + 16777216;
  float* hn = ws + 20971520;

  init_hn_kernel<<<4096, 256, 0, stream>>>((float4*)hn);
  gemm_xp_kernel<<<dim3(64, 64), 256, 0, stream>>>(x, W_ih, b_ih, b_hh, xp);
  gemm_uf_kernel<<<dim3(64, 16), 256, 0, stream>>>(uavf, uavW1, uavb1, uavW2, uavb2, uf);
  scan_kernel<<<kNB, 1024, 0, stream>>>(xp, uf, hn, W_hh, deltas, Wd, ln_g, ln_b, out);
  final_kernel<<<kS, 256, 0, stream>>>(hn, ufcW, ufcb, ln_g, ln_b, out);
}

// Round 4
// 10492.017 us; speedup vs baseline: 2.1063x; 2.1063x over previous
//
#include <hip/hip_runtime.h>
#include <math.h>

// ---------------------------------------------------------------------------
// UAVEnhancedModel: LSTM-with-decay + per-step LayerNorm recurrence (S=4096,
// I=512, H=1024) + uav feature path + sigmoid head.
//
//   1) gemm_xp: x_proj = x @ W_ih^T + (b_ih+b_hh), stored GATE-INTERLEAVED:
//      xpg[s][u][g] (so one block's 16 gate values = one 64B line).
//   2) gemm_uf: uf = relu(uav*W1^T + b1) @ W2^T + b2          [4096, 1024]
//   3) scan: 256 blocks x 256 threads (1 block/CU). Block b owns units
//      j0..j0+3 (XCD-chunked swizzle), wave w <-> unit j0+w; lane group
//      g (16 lanes) <-> gate row g*1024+unit; 64 W_hh*ln_g weights/thread
//      in VGPRs. Sync is DATA-FLOW: hn[] sentinel-filled; producers (lane 0
//      per wave) publish h via agent-scope dword stores; every thread polls
//      its own 16B of hn[t-1] with ONE global_load_dwordx4 sc0 sc1 per sweep
//      (all 4 words checked -> no ordering/tearing assumption).
//      LN folded into the matvec: gates = xp + rstd*(dot(W*g,h) - mu*Ar)+Br.
//      ONE __syncthreads per step (parity double-buffered LDS row).
//   4) final: out[t] = sigmoid(ufcW @ h_ln_t + ufcb); also h_last, c_last.
// ---------------------------------------------------------------------------

constexpr int kS  = 4096;
constexpr int kI  = 512;
constexpr int kH  = 1024;
constexpr int kG4 = 4096;   // 4*kH
constexpr int kNB = 256;    // scan blocks (1 per CU)
constexpr float kLnEps = 1e-5f;
constexpr float kWdEps = 1e-7f;
constexpr float kSent  = 1e30f;   // h clipped to [-10,10] -> unreachable

typedef float f4 __attribute__((ext_vector_type(4)));

__device__ __forceinline__ float sigm(float x) { return 1.f / (1.f + expf(-x)); }

// ---------------- init: fill hn with sentinel ----------------
__global__ __launch_bounds__(256) void init_hn_kernel(float4* __restrict__ p) {
  const int i = blockIdx.x * 256 + threadIdx.x;   // 4096*256 float4 = S*H
  p[i] = make_float4(kSent, kSent, kSent, kSent);
}

// -------- GEMM1: xpg[s][u][g] = sum_k x[s,k]*W_ih[g*1024+u,k] + bias ------
__global__ __launch_bounds__(256) void gemm_xp_kernel(
    const float* __restrict__ A,     // x [4096,512]
    const float* __restrict__ B,     // W_ih [4096,512]
    const float* __restrict__ b_ih, const float* __restrict__ b_hh,
    float* __restrict__ C)           // xpg [4096][1024][4]
{
  __shared__ float As[32][68];
  __shared__ float Bs[32][68];
  const int bm = blockIdx.x * 64, bn = blockIdx.y * 64;
  const int tid = threadIdx.x;
  const int tx = tid & 15, ty = tid >> 4;
  float acc[4][4] = {};
  for (int k0 = 0; k0 < kI; k0 += 32) {
#pragma unroll
    for (int h = 0; h < 2; ++h) {
      const int f = tid + h * 256;
      const int row = f >> 3, c4 = (f & 7) * 4;
      const float4 a  = *(const float4*)(A + (size_t)(bm + row) * kI + k0 + c4);
      const float4 bb = *(const float4*)(B + (size_t)(bn + row) * kI + k0 + c4);
      As[c4 + 0][row] = a.x;  As[c4 + 1][row] = a.y;
      As[c4 + 2][row] = a.z;  As[c4 + 3][row] = a.w;
      Bs[c4 + 0][row] = bb.x; Bs[c4 + 1][row] = bb.y;
      Bs[c4 + 2][row] = bb.z; Bs[c4 + 3][row] = bb.w;
    }
    __syncthreads();
#pragma unroll
    for (int k = 0; k < 32; ++k) {
      const float4 a  = *(const float4*)&As[k][ty * 4];
      const float4 bb = *(const float4*)&Bs[k][tx * 4];
      const float av[4] = {a.x, a.y, a.z, a.w};
      const float bv[4] = {bb.x, bb.y, bb.z, bb.w};
#pragma unroll
      for (int i = 0; i < 4; ++i)
#pragma unroll
        for (int j = 0; j < 4; ++j) acc[i][j] += av[i] * bv[j];
    }
    __syncthreads();
  }
  const float4 bi = *(const float4*)(b_ih + bn + tx * 4);
  const float4 bh = *(const float4*)(b_hh + bn + tx * 4);
  const float bias[4] = {bi.x + bh.x, bi.y + bh.y, bi.z + bh.z, bi.w + bh.w};
  const int gate = bn >> 10;            // 64 | 1024 -> constant per block
  const int ubase = (bn & 1023) + tx * 4;
#pragma unroll
  for (int i = 0; i < 4; ++i) {
    float* dst = C + (size_t)(bm + ty * 4 + i) * kG4 + (size_t)ubase * 4 + gate;
#pragma unroll
    for (int j = 0; j < 4; ++j) dst[4 * j] = acc[i][j] + bias[j];
  }
}

// ---------------- GEMM2: uf = relu(uav*W1^T + b1) @ W2^T + b2 --------------
__global__ __launch_bounds__(256) void gemm_uf_kernel(
    const float* __restrict__ uav,
    const float* __restrict__ W1, const float* __restrict__ b1,
    const float* __restrict__ W2,
    const float* __restrict__ b2,
    float* __restrict__ C)           // uf [4096,1024]
{
  __shared__ float As[32][68];
  __shared__ float Bs[32][68];
  __shared__ float uav_s[64];
  const int bm = blockIdx.x * 64, bn = blockIdx.y * 64;
  const int tid = threadIdx.x;
  const int tx = tid & 15, ty = tid >> 4;
  if (tid < 64) uav_s[tid] = uav[bm + tid];
  __syncthreads();
  float acc[4][4] = {};
  for (int k0 = 0; k0 < kH; k0 += 32) {
#pragma unroll
    for (int h = 0; h < 2; ++h) {
      const int f = tid + h * 256;
      const int row = f >> 3, c4 = (f & 7) * 4;
      const float4 w1v = *(const float4*)(W1 + k0 + c4);
      const float4 b1v = *(const float4*)(b1 + k0 + c4);
      const float ua = uav_s[row];
      As[c4 + 0][row] = fmaxf(ua * w1v.x + b1v.x, 0.f);
      As[c4 + 1][row] = fmaxf(ua * w1v.y + b1v.y, 0.f);
      As[c4 + 2][row] = fmaxf(ua * w1v.z + b1v.z, 0.f);
      As[c4 + 3][row] = fmaxf(ua * w1v.w + b1v.w, 0.f);
      const float4 bb = *(const float4*)(W2 + (size_t)(bn + row) * kH + k0 + c4);
      Bs[c4 + 0][row] = bb.x; Bs[c4 + 1][row] = bb.y;
      Bs[c4 + 2][row] = bb.z; Bs[c4 + 3][row] = bb.w;
    }
    __syncthreads();
#pragma unroll
    for (int k = 0; k < 32; ++k) {
      const float4 a  = *(const float4*)&As[k][ty * 4];
      const float4 bb = *(const float4*)&Bs[k][tx * 4];
      const float av[4] = {a.x, a.y, a.z, a.w};
      const float bv[4] = {bb.x, bb.y, bb.z, bb.w};
#pragma unroll
      for (int i = 0; i < 4; ++i)
#pragma unroll
        for (int j = 0; j < 4; ++j) acc[i][j] += av[i] * bv[j];
    }
    __syncthreads();
  }
  const float4 b2v = *(const float4*)(b2 + bn + tx * 4);
#pragma unroll
  for (int i = 0; i < 4; ++i) {
    float4 o = make_float4(acc[i][0] + b2v.x, acc[i][1] + b2v.y,
                           acc[i][2] + b2v.z, acc[i][3] + b2v.w);
    *(float4*)(C + (size_t)(bm + ty * 4 + i) * kH + bn + tx * 4) = o;
  }
}

// ---------------- persistent scan kernel ----------------
// 256 blocks x 256 threads (4 waves). Block b: units j0..j0+3 with
// j0 = ((b&7)*32 + b/8)*4 (XCD-chunked). Wave w <-> unit j0+w; lane group
// g = gate row g*kH+unit. Thread (g,idx): w[4mm+e] =
// W_hh[row][4idx+64mm+e]*ln_g[...]. Poll: thread covers hn words
// [wid*256+4*lane .. +3] with one dwordx4 sc0 sc1 load per sweep.
__global__ __launch_bounds__(256) void scan_kernel(
    const float* __restrict__ xpg,    // [S][H][4] ws
    const float* __restrict__ uf,     // [S,H]  ws
    float* hn,                        // [S,H]  ws (sentinel-initialized)
    const float* __restrict__ W_hh,   // [4H,H]
    const float* __restrict__ deltas, // [S]
    const float* __restrict__ Wd,     // [H]
    const float* __restrict__ ln_g,   // [H]
    const float* __restrict__ ln_b,   // [H]
    float* __restrict__ out)          // d_out (c_last slice)
{
  const int b = blockIdx.x;
  const int tid = threadIdx.x;
  const int wid = tid >> 6, lane = tid & 63;
  const int g = lane >> 4, idx = lane & 15;
  const int j0 = (((b & 7) << 5) | (b >> 3)) << 2;   // XCD-chunked unit base
  const int unit = j0 + wid;
  const int row = g * kH + unit;

  __shared__ float hbuf[2][kH];
  __shared__ float red1[2][4], red2[2][4];

  // --- weights (scaled by ln_g) + folded constants Ar, Br ---
  float w[64];
  float Ar = 0.f, Br = 0.f;
#pragma unroll
  for (int mm = 0; mm < 16; ++mm) {
    const int base = 4 * idx + 64 * mm;
    const float4 wv  = *(const float4*)(W_hh + (size_t)row * kH + base);
    const float4 gg4 = *(const float4*)(ln_g + base);
    const float4 bb4 = *(const float4*)(ln_b + base);
    Br += wv.x * bb4.x + wv.y * bb4.y + wv.z * bb4.z + wv.w * bb4.w;
    w[4 * mm + 0] = wv.x * gg4.x; w[4 * mm + 1] = wv.y * gg4.y;
    w[4 * mm + 2] = wv.z * gg4.z; w[4 * mm + 3] = wv.w * gg4.w;
    Ar += w[4 * mm + 0] + w[4 * mm + 1] + w[4 * mm + 2] + w[4 * mm + 3];
  }
#pragma unroll
  for (int d = 1; d < 16; d <<= 1) {
    Ar += __shfl_xor(Ar, d, 64);
    Br += __shfl_xor(Br, d, 64);
  }

  const float wdc = fminf(fmaxf(Wd[unit], kWdEps), 10.f);  // uniform per wave
  float c_state = 0.f;

  for (int t = 0; t < kS; ++t) {
    const int buf = t & 1;
    // ---- register prefetch (broadcast lines; latency hides under poll) ----
    float gatev = xpg[(size_t)t * kG4 + unit * 4 + g];   // 1 line per block
    const float dl = deltas[t];
    float uf_r = 0.f;
    if (lane == 0) uf_r = uf[(size_t)t * kH + unit];

    if (t > 0) {
      // ---- data-flow gather: one dwordx4 per thread per sweep ----
      const float* hp = hn + (size_t)(t - 1) * kH + (wid << 8) + (lane << 2);
      f4 q;
      for (;;) {
        asm volatile("global_load_dwordx4 %0, %1, off sc0 sc1"
                     : "=v"(q) : "v"(hp) : "memory");
        asm volatile("s_waitcnt vmcnt(0)" ::: "memory");
        if (q.x != kSent && q.y != kSent && q.z != kSent && q.w != kSent) break;
      }
      *(f4*)&hbuf[buf][(wid << 8) + (lane << 2)] = q;
      float s1 = q.x + q.y + q.z + q.w;
      float s2 = q.x * q.x + q.y * q.y + q.z * q.z + q.w * q.w;
#pragma unroll
      for (int d = 1; d < 64; d <<= 1) {
        s1 += __shfl_xor(s1, d, 64);
        s2 += __shfl_xor(s2, d, 64);
      }
      if (lane == 0) { red1[buf][wid] = s1; red2[buf][wid] = s2; }
    }
    __syncthreads();   // single barrier per step

    if (t > 0) {
      const float S1 = red1[buf][0] + red1[buf][1] + red1[buf][2] + red1[buf][3];
      const float S2 = red2[buf][0] + red2[buf][1] + red2[buf][2] + red2[buf][3];
      const float mu = S1 * (1.f / kH);
      const float var = S2 * (1.f / kH) - mu * mu;
      const float rstd = 1.f / sqrtf(var + kLnEps);
      float acc = 0.f;
#pragma unroll
      for (int mm = 0; mm < 16; ++mm) {
        const float4 h4 = *(const float4*)&hbuf[buf][4 * idx + 64 * mm];
        acc += w[4 * mm + 0] * h4.x + w[4 * mm + 1] * h4.y +
               w[4 * mm + 2] * h4.z + w[4 * mm + 3] * h4.w;
      }
#pragma unroll
      for (int d = 1; d < 16; d <<= 1) acc += __shfl_xor(acc, d, 64);
      gatev += rstd * (acc - mu * Ar) + Br;
    }
    // nonlinearity for all 4 gates in one shared chain: tanh(x)=2*sigm(2x)-1
    const float scl = (g == 2) ? 2.f : 1.f;
    const float y = sigm(scl * gatev);
    const float val = (g == 2) ? 2.f * y - 1.f : y;   // i,f,o: sigm; g: tanh
    const float f_ = __shfl(val, 16, 64);
    const float g_ = __shfl(val, 32, 64);
    const float o_ = __shfl(val, 48, 64);
    if (lane == 0) {
      const float dec = expf(-dl * wdc);
      const float cu = f_ * (c_state * dec) + val * g_;     // val = sigm(i)
      const float th = 2.f * sigm(2.f * cu) - 1.f;          // tanh(unclipped c)
      float hv = o_ * th + 1.5f * uf_r;
      hv = fminf(fmaxf(hv, -10.f), 10.f);
      __hip_atomic_store(hn + (size_t)t * kH + unit, hv,
                         __ATOMIC_RELAXED, __HIP_MEMORY_SCOPE_AGENT);
      c_state = fminf(fmaxf(cu, -10.f), 10.f);
    }
  }
  if (lane == 0) out[kS + kH + unit] = c_state;   // c_last
}

// ---------------- final pass: out[t], h_last ----------------
__global__ __launch_bounds__(256) void final_kernel(
    const float* __restrict__ hn, const float* __restrict__ ufcW,
    const float* __restrict__ ufcb, const float* __restrict__ ln_g,
    const float* __restrict__ ln_b, float* __restrict__ out)
{
  const int t = blockIdx.x, tid = threadIdx.x;
  __shared__ float red[4][5];
  __shared__ float muv[2];
  const float4 hv = *(const float4*)(hn + (size_t)t * kH + 4 * tid);
  const float4 uw = *(const float4*)(ufcW + 4 * tid);
  const float4 g4 = *(const float4*)(ln_g + 4 * tid);
  const float4 b4 = *(const float4*)(ln_b + 4 * tid);
  float s1 = hv.x + hv.y + hv.z + hv.w;
  float s2 = hv.x * hv.x + hv.y * hv.y + hv.z * hv.z + hv.w * hv.w;
  float p  = uw.x * g4.x * hv.x + uw.y * g4.y * hv.y + uw.z * g4.z * hv.z + uw.w * g4.w * hv.w;
  float uu = uw.x * g4.x + uw.y * g4.y + uw.z * g4.z + uw.w * g4.w;
  float cc = uw.x * b4.x + uw.y * b4.y + uw.z * b4.z + uw.w * b4.w;
#pragma unroll
  for (int d = 1; d < 64; d <<= 1) {
    s1 += __shfl_xor(s1, d, 64); s2 += __shfl_xor(s2, d, 64);
    p  += __shfl_xor(p, d, 64);  uu += __shfl_xor(uu, d, 64);
    cc += __shfl_xor(cc, d, 64);
  }
  if ((tid & 63) == 0) {
    const int wv = tid >> 6;
    red[wv][0] = s1; red[wv][1] = s2; red[wv][2] = p; red[wv][3] = uu; red[wv][4] = cc;
  }
  __syncthreads();
  if (tid == 0) {
    float S1 = 0, S2 = 0, P = 0, U = 0, C = 0;
    for (int wv = 0; wv < 4; ++wv) {
      S1 += red[wv][0]; S2 += red[wv][1]; P += red[wv][2];
      U += red[wv][3];  C += red[wv][4];
    }
    const float mu = S1 * (1.f / kH);
    const float var = S2 * (1.f / kH) - mu * mu;
    const float rstd = 1.f / sqrtf(var + kLnEps);
    const float val = rstd * (P - mu * U) + C + ufcb[0];
    out[t] = 1.f / (1.f + expf(-val));
    muv[0] = mu; muv[1] = rstd;
  }
  if (t == kS - 1) {   // h_last = h_ln of final step
    __syncthreads();
    const float mu = muv[0], rstd = muv[1];
    out[kS + 4 * tid + 0] = (hv.x - mu) * rstd * g4.x + b4.x;
    out[kS + 4 * tid + 1] = (hv.y - mu) * rstd * g4.y + b4.y;
    out[kS + 4 * tid + 2] = (hv.z - mu) * rstd * g4.z + b4.z;
    out[kS + 4 * tid + 3] = (hv.w - mu) * rstd * g4.w + b4.w;
  }
}

// ---------------- launch ----------------
extern "C" void kernel_launch(void* const* d_in, const int* in_sizes, int n_in,
                              void* d_out, int out_size, void* d_ws, size_t ws_size,
                              hipStream_t stream) {
  (void)in_sizes; (void)n_in; (void)out_size; (void)ws_size;
  const float* x      = (const float*)d_in[0];
  const float* deltas = (const float*)d_in[1];
  const float* uavf   = (const float*)d_in[2];
  const float* W_ih   = (const float*)d_in[3];
  const float* W_hh   = (const float*)d_in[4];
  const float* b_ih   = (const float*)d_in[5];
  const float* b_hh   = (const float*)d_in[6];
  const float* Wd     = (const float*)d_in[7];
  const float* uavW1  = (const float*)d_in[8];
  const float* uavb1  = (const float*)d_in[9];
  const float* uavW2  = (const float*)d_in[10];
  const float* uavb2  = (const float*)d_in[11];
  const float* ufcW   = (const float*)d_in[12];
  const float* ufcb   = (const float*)d_in[13];
  const float* ln_g   = (const float*)d_in[14];
  const float* ln_b   = (const float*)d_in[15];
  float* out = (float*)d_out;

  // ws layout (floats): xpg 16777216 | uf 4194304 | hn 4194304
  float* ws = (float*)d_ws;
  float* xpg = ws;
  float* uf  = ws + 16777216;
  float* hn  = ws + 20971520;

  init_hn_kernel<<<4096, 256, 0, stream>>>((float4*)hn);
  gemm_xp_kernel<<<dim3(64, 64), 256, 0, stream>>>(x, W_ih, b_ih, b_hh, xpg);
  gemm_uf_kernel<<<dim3(64, 16), 256, 0, stream>>>(uavf, uavW1, uavb1, uavW2, uavb2, uf);
  scan_kernel<<<kNB, 256, 0, stream>>>(xpg, uf, hn, W_hh, deltas, Wd, ln_g, ln_b, out);
  final_kernel<<<kS, 256, 0, stream>>>(hn, ufcW, ufcb, ln_g, ln_b, out);
}